// Round 1
// baseline (4787.141 us; speedup 1.0000x reference)
//
#include <hip/hip_runtime.h>

// Problem constants (match reference).
#define E_TOT   500000
#define N_NEW_  100000
#define H_      128
#define D_      100

__device__ __forceinline__ float dot4(float4 a, float4 b) {
  return a.x * b.x + a.y * b.y + a.z * b.z + a.w * b.w;
}
// Order-preserving float<->uint encoding for atomicMax-based segment max.
__device__ __forceinline__ unsigned encf(float f) {
  unsigned u = __float_as_uint(f);
  return (u & 0x80000000u) ? ~u : (u | 0x80000000u);
}
__device__ __forceinline__ float decf(unsigned e) {
  unsigned u = (e & 0x80000000u) ? (e & 0x7fffffffu) : ~e;
  return __uint_as_float(u);
}
__device__ __forceinline__ float sigmoidf_(float x) { return 1.f / (1.f + expf(-x)); }

// dst[c*R + r] = src[r*C + c]  (weights -> [K][out] layout for coalesced lane reads)
__global__ void k_transpose(const float* __restrict__ src, float* __restrict__ dst, int R, int C) {
  int idx = blockIdx.x * 256 + threadIdx.x;
  if (idx < R * C) {
    int r = idx / C, c = idx - r * C;
    dst[(size_t)c * R + r] = src[idx];
  }
}

// ---- Kernel 1: per-edge attention logit + segment max (atomicMax on encoded float) ----
// 32 edges/block, 256 thr. Thread tile: 4 edges x 4 outs (outs blocked, lane-contiguous).
__global__ __launch_bounds__(256) void k_logit(
    const int* __restrict__ head, const int* __restrict__ rel, const int* __restrict__ qidx,
    const int* __restrict__ tail,
    const float* __restrict__ node_emb, const float* __restrict__ rel_table,
    const float* __restrict__ WsT, const float* __restrict__ WrT, const float* __restrict__ WqrT,
    const float* __restrict__ b_qr, const float* __restrict__ Wa, const float* __restrict__ b_a,
    float* __restrict__ logit, unsigned* __restrict__ smax)
{
  __shared__ __align__(16) float hs_s[32][H_];
  __shared__ __align__(16) float hr_s[32][D_];
  __shared__ __align__(16) float qr_s[32][D_];
  const int tid = threadIdx.x;
  const int e0 = blockIdx.x * 32;

  for (int idx = tid; idx < 32 * H_; idx += 256) {
    int e = idx >> 7, j = idx & (H_ - 1);
    hs_s[e][j] = node_emb[(size_t)head[e0 + e] * H_ + j];
  }
  for (int idx = tid; idx < 32 * D_; idx += 256) {
    int e = idx / D_, j = idx - e * D_;
    hr_s[e][j] = rel_table[rel[e0 + e] * D_ + j];
    qr_s[e][j] = rel_table[qidx[e0 + e] * D_ + j];
  }
  __syncthreads();

  const int itile = tid & 31, etile = tid >> 5;
  const int eb = etile * 4;
  float acc[4][4] = {};

  // hs @ Ws^T  (K = 128)
  for (int k4 = 0; k4 < H_ / 4; ++k4) {
    float4 a[4];
#pragma unroll
    for (int d = 0; d < 4; ++d) a[d] = ((const float4*)hs_s[eb + d])[k4];
#pragma unroll
    for (int kk = 0; kk < 4; ++kk) {
      float4 w = ((const float4*)(WsT + (size_t)(k4 * 4 + kk) * H_))[itile];
#pragma unroll
      for (int d = 0; d < 4; ++d) {
        float av = ((const float*)&a[d])[kk];
        acc[d][0] += av * w.x; acc[d][1] += av * w.y;
        acc[d][2] += av * w.z; acc[d][3] += av * w.w;
      }
    }
  }
  // hr @ Wr^T + qr @ Wqr^T  (K = 100)
  for (int k4 = 0; k4 < D_ / 4; ++k4) {
    float4 a[4], b[4];
#pragma unroll
    for (int d = 0; d < 4; ++d) {
      a[d] = ((const float4*)hr_s[eb + d])[k4];
      b[d] = ((const float4*)qr_s[eb + d])[k4];
    }
#pragma unroll
    for (int kk = 0; kk < 4; ++kk) {
      float4 wr = ((const float4*)(WrT + (size_t)(k4 * 4 + kk) * H_))[itile];
      float4 wq = ((const float4*)(WqrT + (size_t)(k4 * 4 + kk) * H_))[itile];
#pragma unroll
      for (int d = 0; d < 4; ++d) {
        float ar = ((const float*)&a[d])[kk];
        float aq = ((const float*)&b[d])[kk];
        acc[d][0] += ar * wr.x + aq * wq.x;
        acc[d][1] += ar * wr.y + aq * wq.y;
        acc[d][2] += ar * wr.z + aq * wq.z;
        acc[d][3] += ar * wr.w + aq * wq.w;
      }
    }
  }

  // logit_e = sum_i Wa[i]*relu(pre[e][i]) + b_a ; per-thread partial over its 4 i's
  float part[4] = {0.f, 0.f, 0.f, 0.f};
#pragma unroll
  for (int ii = 0; ii < 4; ++ii) {
    int i = itile * 4 + ii;
    float bi = b_qr[i], wa = Wa[i];
#pragma unroll
    for (int d = 0; d < 4; ++d)
      part[d] += wa * fmaxf(acc[d][ii] + bi, 0.f);
  }
  // reduce across the 32 contiguous lanes sharing this edge group
#pragma unroll
  for (int off = 1; off < 32; off <<= 1) {
#pragma unroll
    for (int d = 0; d < 4; ++d) part[d] += __shfl_xor(part[d], off);
  }
  if (itile == 0) {
    float ba = b_a[0];
#pragma unroll
    for (int d = 0; d < 4; ++d) {
      int e = e0 + eb + d;
      float lg = part[d] + ba;
      logit[e] = lg;
      atomicMax(&smax[tail[e]], encf(lg));
    }
  }
}

// ---- Kernel 2: ex = exp(logit - segmax[tail]); denom accumulation ----
__global__ __launch_bounds__(256) void k_exden(
    const float* __restrict__ logit, const int* __restrict__ tail,
    const unsigned* __restrict__ smax, float* __restrict__ ex, float* __restrict__ den)
{
  int e = blockIdx.x * 256 + threadIdx.x;
  if (e < E_TOT) {
    int t = tail[e];
    float v = expf(logit[e] - decf(smax[t]));
    ex[e] = v;
    atomicAdd(&den[t], v);
  }
}

// ---- Kernel 3: GRU message + alpha-weighted scatter-add into agg (= d_out) ----
// 16 edges/block. Thread tile: 2 edges x (4 h's x 3 gates); gate rows for the same h
// live in the same thread so the gate nonlinearity needs no cross-thread exchange.
__global__ __launch_bounds__(256) void k_msgagg(
    const int* __restrict__ head, const int* __restrict__ rel, const int* __restrict__ ent,
    const int* __restrict__ tail,
    const float* __restrict__ node_emb, const float* __restrict__ ent_table,
    const float* __restrict__ rel_table,
    const float* __restrict__ WihT, const float* __restrict__ WhhT,
    const float* __restrict__ b_ih, const float* __restrict__ b_hh,
    const float* __restrict__ ex, const float* __restrict__ den, float* __restrict__ agg)
{
  __shared__ __align__(16) float x_s[16][2 * D_];   // [he | hr]
  __shared__ __align__(16) float hs_s[16][H_];
  __shared__ float al_s[16];
  __shared__ int tl_s[16];
  const int tid = threadIdx.x;
  const int e0 = blockIdx.x * 16;

  for (int idx = tid; idx < 16 * D_; idx += 256) {
    int e = idx / D_, j = idx - e * D_;
    x_s[e][j]      = ent_table[(size_t)ent[e0 + e] * D_ + j];
    x_s[e][D_ + j] = rel_table[rel[e0 + e] * D_ + j];
  }
  for (int idx = tid; idx < 16 * H_; idx += 256) {
    int e = idx >> 7, j = idx & (H_ - 1);
    hs_s[e][j] = node_emb[(size_t)head[e0 + e] * H_ + j];
  }
  if (tid < 16) {
    int t = tail[e0 + tid];
    tl_s[tid] = t;
    al_s[tid] = ex[e0 + tid] / (den[t] + 1e-6f);
  }
  __syncthreads();

  const int col = tid & 31, eg = tid >> 5;
  float ax[2][3][4] = {};   // [edge][gate r/z/n][h-sub]
  float ah[2][3][4] = {};

  // gx = x @ W_ih^T (K = 200)
  for (int k4 = 0; k4 < (2 * D_) / 4; ++k4) {
    float4 a0 = ((const float4*)x_s[2 * eg])[k4];
    float4 a1 = ((const float4*)x_s[2 * eg + 1])[k4];
#pragma unroll
    for (int kk = 0; kk < 4; ++kk) {
      const float4* wrow = (const float4*)(WihT + (size_t)(k4 * 4 + kk) * 384);
      float v0 = ((const float*)&a0)[kk];
      float v1 = ((const float*)&a1)[kk];
#pragma unroll
      for (int g = 0; g < 3; ++g) {
        float4 w = wrow[g * 32 + col];
        ax[0][g][0] += v0 * w.x; ax[0][g][1] += v0 * w.y;
        ax[0][g][2] += v0 * w.z; ax[0][g][3] += v0 * w.w;
        ax[1][g][0] += v1 * w.x; ax[1][g][1] += v1 * w.y;
        ax[1][g][2] += v1 * w.z; ax[1][g][3] += v1 * w.w;
      }
    }
  }
  // gh = hs @ W_hh^T (K = 128)
  for (int k4 = 0; k4 < H_ / 4; ++k4) {
    float4 a0 = ((const float4*)hs_s[2 * eg])[k4];
    float4 a1 = ((const float4*)hs_s[2 * eg + 1])[k4];
#pragma unroll
    for (int kk = 0; kk < 4; ++kk) {
      const float4* wrow = (const float4*)(WhhT + (size_t)(k4 * 4 + kk) * 384);
      float v0 = ((const float*)&a0)[kk];
      float v1 = ((const float*)&a1)[kk];
#pragma unroll
      for (int g = 0; g < 3; ++g) {
        float4 w = wrow[g * 32 + col];
        ah[0][g][0] += v0 * w.x; ah[0][g][1] += v0 * w.y;
        ah[0][g][2] += v0 * w.z; ah[0][g][3] += v0 * w.w;
        ah[1][g][0] += v1 * w.x; ah[1][g][1] += v1 * w.y;
        ah[1][g][2] += v1 * w.z; ah[1][g][3] += v1 * w.w;
      }
    }
  }

#pragma unroll
  for (int l = 0; l < 2; ++l) {
    int le = 2 * eg + l;
    float alpha = al_s[le];
    size_t base = (size_t)tl_s[le] * H_;
#pragma unroll
    for (int q = 0; q < 4; ++q) {
      int h = col * 4 + q;
      float r = sigmoidf_(ax[l][0][q] + b_ih[h]          + ah[l][0][q] + b_hh[h]);
      float z = sigmoidf_(ax[l][1][q] + b_ih[H_ + h]     + ah[l][1][q] + b_hh[H_ + h]);
      float n = tanhf(    ax[l][2][q] + b_ih[2 * H_ + h] + r * (ah[l][2][q] + b_hh[2 * H_ + h]));
      float msg = (1.f - z) * n + z * hs_s[le][h];
      atomicAdd(&agg[base + h], alpha * msg);
    }
  }
}

// ---- Kernel 4: out = LayerNorm(relu(agg @ Wh^T)), in place over d_out, 16 rows/block ----
__global__ __launch_bounds__(256) void k_out(
    const float* __restrict__ WhT, const float* __restrict__ ln_g, const float* __restrict__ ln_b,
    float* __restrict__ out)
{
  __shared__ __align__(16) float a_s[16][H_];
  __shared__ float o_s[16][H_];
  __shared__ float mu_s[16], rs_s[16];
  const int tid = threadIdx.x;
  const size_t r0 = (size_t)blockIdx.x * 16;

  for (int idx = tid; idx < 16 * H_; idx += 256) {
    int r = idx >> 7, j = idx & (H_ - 1);
    a_s[r][j] = out[(r0 + r) * H_ + j];
  }
  __syncthreads();

  const int col = tid & 15, rr = tid >> 4;
  float acc[8] = {};
  for (int k4 = 0; k4 < H_ / 4; ++k4) {
    float4 a = ((const float4*)a_s[rr])[k4];
#pragma unroll
    for (int kk = 0; kk < 4; ++kk) {
      const float4* wrow = (const float4*)(WhT + (size_t)(k4 * 4 + kk) * H_);
      float av = ((const float*)&a)[kk];
      float4 w0 = wrow[col];
      float4 w1 = wrow[16 + col];
      acc[0] += av * w0.x; acc[1] += av * w0.y; acc[2] += av * w0.z; acc[3] += av * w0.w;
      acc[4] += av * w1.x; acc[5] += av * w1.y; acc[6] += av * w1.z; acc[7] += av * w1.w;
    }
  }
  float s = 0.f, sq = 0.f;
#pragma unroll
  for (int c = 0; c < 8; ++c) {
    float v = fmaxf(acc[c], 0.f);
    acc[c] = v; s += v; sq += v * v;
  }
#pragma unroll
  for (int c = 0; c < 4; ++c) {
    o_s[rr][col * 4 + c]      = acc[c];
    o_s[rr][64 + col * 4 + c] = acc[4 + c];
  }
#pragma unroll
  for (int off = 1; off < 16; off <<= 1) { s += __shfl_xor(s, off); sq += __shfl_xor(sq, off); }
  if (col == 0) {
    float mu = s * (1.f / H_);
    mu_s[rr] = mu;
    rs_s[rr] = rsqrtf(sq * (1.f / H_) - mu * mu + 1e-5f);
  }
  __syncthreads();
  for (int idx = tid; idx < 16 * H_; idx += 256) {
    int r = idx >> 7, j = idx & (H_ - 1);
    out[(r0 + r) * H_ + j] = ln_g[j] * (o_s[r][j] - mu_s[r]) * rs_s[r] + ln_b[j];
  }
}

extern "C" void kernel_launch(void* const* d_in, const int* in_sizes, int n_in,
                              void* d_out, int out_size, void* d_ws, size_t ws_size,
                              hipStream_t stream) {
  (void)in_sizes; (void)n_in; (void)ws_size;
  const int* head = (const int*)d_in[0];
  const int* rel  = (const int*)d_in[1];
  const int* ent  = (const int*)d_in[2];
  const int* tail = (const int*)d_in[3];
  const int* qidx = (const int*)d_in[4];
  const float* node_emb  = (const float*)d_in[5];
  const float* ent_table = (const float*)d_in[6];
  const float* rel_table = (const float*)d_in[7];
  const float* Ws   = (const float*)d_in[8];
  const float* Wr   = (const float*)d_in[9];
  const float* Wqr  = (const float*)d_in[10];
  const float* b_qr = (const float*)d_in[11];
  const float* Wa   = (const float*)d_in[12];
  const float* b_a  = (const float*)d_in[13];
  const float* W_ih = (const float*)d_in[14];
  const float* W_hh = (const float*)d_in[15];
  const float* b_ih = (const float*)d_in[16];
  const float* b_hh = (const float*)d_in[17];
  const float* Wh   = (const float*)d_in[18];
  const float* ln_g = (const float*)d_in[19];
  const float* ln_b = (const float*)d_in[20];
  float* out = (float*)d_out;

  // Workspace layout (floats): logit[E] | ex[E] | smax[N] | den[N] | transposed weights
  float* ws_logit   = (float*)d_ws;
  float* ws_ex      = ws_logit + E_TOT;
  unsigned* ws_smax = (unsigned*)(ws_ex + E_TOT);
  float* ws_den     = (float*)(ws_smax + N_NEW_);
  float* WsT  = ws_den + N_NEW_;
  float* WrT  = WsT  + 128 * 128;
  float* WqrT = WrT  + 100 * 128;
  float* WihT = WqrT + 100 * 128;
  float* WhhT = WihT + 200 * 384;
  float* WhT  = WhhT + 128 * 384;

  hipMemsetAsync(ws_smax, 0, 2 * N_NEW_ * sizeof(float), stream);  // smax(enc=0 == -inf) + den
  hipMemsetAsync(d_out, 0, (size_t)out_size * sizeof(float), stream);  // agg accumulator

  k_transpose<<<(128 * 128 + 255) / 256, 256, 0, stream>>>(Ws,   WsT,  128, 128);
  k_transpose<<<(128 * 100 + 255) / 256, 256, 0, stream>>>(Wr,   WrT,  128, 100);
  k_transpose<<<(128 * 100 + 255) / 256, 256, 0, stream>>>(Wqr,  WqrT, 128, 100);
  k_transpose<<<(384 * 200 + 255) / 256, 256, 0, stream>>>(W_ih, WihT, 384, 200);
  k_transpose<<<(384 * 128 + 255) / 256, 256, 0, stream>>>(W_hh, WhhT, 384, 128);
  k_transpose<<<(128 * 128 + 255) / 256, 256, 0, stream>>>(Wh,   WhT,  128, 128);

  k_logit<<<E_TOT / 32, 256, 0, stream>>>(head, rel, qidx, tail, node_emb, rel_table,
                                          WsT, WrT, WqrT, b_qr, Wa, b_a, ws_logit, ws_smax);
  k_exden<<<(E_TOT + 255) / 256, 256, 0, stream>>>(ws_logit, tail, ws_smax, ws_ex, ws_den);
  k_msgagg<<<E_TOT / 16, 256, 0, stream>>>(head, rel, ent, tail, node_emb, ent_table, rel_table,
                                           WihT, WhhT, b_ih, b_hh, ws_ex, ws_den, out);
  k_out<<<N_NEW_ / 16, 256, 0, stream>>>(WhT, ln_g, ln_b, out);
}

// Round 2
// 1827.670 us; speedup vs baseline: 2.6193x; 2.6193x over previous
//
#include <hip/hip_runtime.h>

// Problem constants.
#define E_TOT   500000
#define N_NEW_  100000
#define H_      128
#define D_      100

typedef short bf16x8 __attribute__((ext_vector_type(8)));
typedef float f32x4  __attribute__((ext_vector_type(4)));

__device__ __forceinline__ unsigned short f2bf(float f) {
  unsigned u = __float_as_uint(f);
  u += 0x7fffu + ((u >> 16) & 1u);       // RNE
  return (unsigned short)(u >> 16);
}
__device__ __forceinline__ float sigm(float x) { return 1.f / (1.f + expf(-x)); }

// dst[c*R + r] = src[r*C + c]
__global__ void k_transpose(const float* __restrict__ src, float* __restrict__ dst, int R, int C) {
  int idx = blockIdx.x * 256 + threadIdx.x;
  if (idx < R * C) {
    int r = idx / C, c = idx - r * C;
    dst[(size_t)c * R + r] = src[idx];
  }
}

// Build the 640x512 bf16 weight atlas.
// Cols (K): region0 hs[0:128], region1 hr[128:228(+pad)], region2 qr[256:356(+pad)], region3 he[384:484(+pad)]
// Rows (N-chunks of 128): 0 logit (Ws|Wr|Wqr|0), 1 r (Whh_r|Wih_r_hr|0|Wih_r_he),
//   2 z (likewise rows+128), 3 xn (0|Wih_n_hr|0|Wih_n_he), 4 hn (Whh_n|0|0|0)
__global__ void k_prep(const float* __restrict__ Ws, const float* __restrict__ Wr,
                       const float* __restrict__ Wqr, const float* __restrict__ Wih,
                       const float* __restrict__ Whh, unsigned short* __restrict__ Wcat) {
  int idx = blockIdx.x * 256 + threadIdx.x;
  if (idx >= 640 * 512) return;
  int o = idx >> 9, k = idx & 511;
  int rg = k >> 7, cr = k & 127;
  int ch = o >> 7, oo = o & 127;
  float v = 0.f;
  if (ch == 0) {                       // logit rows
    if (rg == 0) v = Ws[oo * 128 + cr];
    else if (rg == 1) { if (cr < 100) v = Wr[oo * 100 + cr]; }
    else if (rg == 2) { if (cr < 100) v = Wqr[oo * 100 + cr]; }
  } else if (ch == 1 || ch == 2) {     // r / z gates: merged ih+hh rows
    int g = (ch - 1) * 128 + oo;       // W row 0..255
    if (rg == 0) v = Whh[g * 128 + cr];
    else if (rg == 1) { if (cr < 100) v = Wih[g * 200 + 100 + cr]; }  // hr is 2nd half of x
    else if (rg == 3) { if (cr < 100) v = Wih[g * 200 + cr]; }        // he is 1st half
  } else if (ch == 3) {                // xn: input part of n-gate only
    int g = 256 + oo;
    if (rg == 1) { if (cr < 100) v = Wih[g * 200 + 100 + cr]; }
    else if (rg == 3) { if (cr < 100) v = Wih[g * 200 + cr]; }
  } else {                             // hn: hidden part of n-gate only
    int g = 256 + oo;
    if (rg == 0) v = Whh[g * 128 + cr];
  }
  Wcat[idx] = f2bf(v);
}

__device__ __forceinline__ void gather8(const float* __restrict__ tbl, const int* __restrict__ idp,
                                        int w, int c0, int e, float g8[8]) {
  bool ev = (e < E_TOT);
  int ix = ev ? idp[e] : 0;
  const float* src = tbl + (size_t)ix * w + c0;
  if (ev && c0 + 8 <= w) {
    float4 v0 = ((const float4*)src)[0];
    float4 v1 = ((const float4*)src)[1];
    g8[0] = v0.x; g8[1] = v0.y; g8[2] = v0.z; g8[3] = v0.w;
    g8[4] = v1.x; g8[5] = v1.y; g8[6] = v1.z; g8[7] = v1.w;
  } else {
#pragma unroll
    for (int j = 0; j < 8; ++j) g8[j] = (ev && (c0 + j) < w) ? src[j] : 0.f;
  }
}

// ---- Fused edge kernel: gather -> bf16 LDS -> MFMA (5 N-chunks) -> logit/exp/den + GRU msg
// ---- -> ex*msg scatter into agg. 128 edges/block, 640 threads = 10 waves (2M x 5N).
__global__ __launch_bounds__(640) void k_edge(
    const int* __restrict__ head, const int* __restrict__ rel, const int* __restrict__ ent,
    const int* __restrict__ tail, const int* __restrict__ qidx,
    const float* __restrict__ node_emb, const float* __restrict__ ent_table,
    const float* __restrict__ rel_table,
    const unsigned short* __restrict__ Wcat,
    const float* __restrict__ b_qr, const float* __restrict__ Wa, const float* __restrict__ b_a,
    const float* __restrict__ b_ih, const float* __restrict__ b_hh,
    float* __restrict__ den, float* __restrict__ agg)
{
  __shared__ __align__(16) char smem[131072];
  unsigned short (*A)[128][40] = (unsigned short (*)[128][40])smem;  // [2][128][40] bf16, padded rows
  float (*G)[64][128] = (float (*)[64][128])smem;                    // [4][64][128] gate exchange
  __shared__ float ex_s[128];

  const int t = threadIdx.x;
  const int wid = t >> 6, lane = t & 63;
  const int c = wid >> 1, wm = wid & 1;     // chunk 0..4, M-half
  const int l15 = lane & 15, l4 = lane >> 4;
  const int e0 = blockIdx.x * 128;
  const int se = t >> 2, q = t & 3;         // stager: edge-in-block, quad
  const bool stager = (t < 512);

  f32x4 acc[4][8];
  const f32x4 zz = {0.f, 0.f, 0.f, 0.f};
#pragma unroll
  for (int i = 0; i < 4; ++i)
#pragma unroll
    for (int j = 0; j < 8; ++j) acc[i][j] = zz;

  float g8[8];

  // prologue: gather + stage kt=0 (hs region)
  if (stager) {
    gather8(node_emb, head, 128, q * 8, e0 + se, g8);
    bf16x8 pk;
#pragma unroll
    for (int j = 0; j < 8; ++j) pk[j] = (short)f2bf(g8[j]);
    *(bf16x8*)&A[0][se][q * 8] = pk;
  }
  __syncthreads();

#pragma unroll
  for (int kt = 0; kt < 16; ++kt) {
    const int buf = kt & 1;
    // T14: issue next tile's gather loads before this tile's MFMA
    if (kt + 1 < 16 && stager) {
      int rg = (kt + 1) >> 2, sub = (kt + 1) & 3;
      const float* tb = (rg == 0) ? node_emb : (rg == 3) ? ent_table : rel_table;
      const int* ip = (rg == 0) ? head : (rg == 1) ? rel : (rg == 2) ? qidx : ent;
      int w = (rg == 0) ? 128 : 100;
      gather8(tb, ip, w, sub * 32 + q * 8, e0 + se, g8);
    }
    // per-chunk K-tile activity (zero weight regions skipped)
    bool act = (c == 0) ? (kt < 12)
             : (c <= 2) ? (kt < 8 || kt >= 12)
             : (c == 3) ? ((kt >= 4 && kt < 8) || kt >= 12)
                        : (kt < 4);
    if (act) {
      bf16x8 bfr[8], afr[4];
#pragma unroll
      for (int ni = 0; ni < 8; ++ni)
        bfr[ni] = *(const bf16x8*)(Wcat + ((size_t)(c * 128 + ni * 16 + l15) * 512 + kt * 32 + l4 * 8));
#pragma unroll
      for (int mi = 0; mi < 4; ++mi)
        afr[mi] = *(const bf16x8*)&A[buf][wm * 64 + mi * 16 + l15][l4 * 8];
#pragma unroll
      for (int mi = 0; mi < 4; ++mi)
#pragma unroll
        for (int ni = 0; ni < 8; ++ni)
          acc[mi][ni] = __builtin_amdgcn_mfma_f32_16x16x32_bf16(afr[mi], bfr[ni], acc[mi][ni], 0, 0, 0);
    }
    __syncthreads();
    if (kt + 1 < 16 && stager) {
      bf16x8 pk;
#pragma unroll
      for (int j = 0; j < 8; ++j) pk[j] = (short)f2bf(g8[j]);
      *(bf16x8*)&A[buf ^ 1][se][q * 8] = pk;
    }
    __syncthreads();
  }

  // ---- epilogue part 1: logit waves -> ex + den atomics; gate waves add biases ----
  if (c == 0) {
    float ba = b_a[0];
#pragma unroll
    for (int mi = 0; mi < 4; ++mi) {
      float p[4] = {0.f, 0.f, 0.f, 0.f};
#pragma unroll
      for (int ni = 0; ni < 8; ++ni) {
        int o = ni * 16 + l15;
        float bq = b_qr[o], wa = Wa[o];
#pragma unroll
        for (int r = 0; r < 4; ++r) p[r] += wa * fmaxf(acc[mi][ni][r] + bq, 0.f);
      }
#pragma unroll
      for (int off = 1; off < 16; off <<= 1) {
#pragma unroll
        for (int r = 0; r < 4; ++r) p[r] += __shfl_xor(p[r], off);
      }
      if (l15 == 0) {
#pragma unroll
        for (int r = 0; r < 4; ++r) {
          int el = wm * 64 + mi * 16 + l4 * 4 + r;
          int e = e0 + el;
          float exv = expf(p[r] + ba);     // no max-sub: |logit| small, folded into den divide
          ex_s[el] = exv;
          if (e < E_TOT) atomicAdd(&den[tail[e]], exv);
        }
      }
    }
  } else {
#pragma unroll
    for (int ni = 0; ni < 8; ++ni) {
      int h = ni * 16 + l15;
      float bias = (c == 1) ? b_ih[h] + b_hh[h]
                 : (c == 2) ? b_ih[128 + h] + b_hh[128 + h]
                 : (c == 3) ? b_ih[256 + h]
                            : b_hh[256 + h];
#pragma unroll
      for (int mi = 0; mi < 4; ++mi)
#pragma unroll
        for (int r = 0; r < 4; ++r) acc[mi][ni][r] += bias;
    }
  }
  __syncthreads();

  // ---- epilogue part 2: two-phase gate exchange + msg + scatter ----
#pragma unroll
  for (int ph = 0; ph < 2; ++ph) {
    if (c >= 1 && wm == ph) {
#pragma unroll
      for (int mi = 0; mi < 4; ++mi)
#pragma unroll
        for (int ni = 0; ni < 8; ++ni)
#pragma unroll
          for (int r = 0; r < 4; ++r)
            G[c - 1][mi * 16 + l4 * 4 + r][ni * 16 + l15] = acc[mi][ni][r];
    }
    __syncthreads();
    for (int it = 0; it < 13; ++it) {
      int idx = it * 640 + t;
      if (idx < 8192) {
        int le = idx >> 7, h = idx & 127;
        int e = e0 + ph * 64 + le;
        if (e < E_TOT) {
          float rr = G[0][le][h], zv = G[1][le][h], xn = G[2][le][h], hn = G[3][le][h];
          float rgate = sigm(rr), zgate = sigm(zv);
          float n = tanhf(xn + rgate * hn);
          float hs = node_emb[(size_t)head[e] * H_ + h];
          float msg = (1.f - zgate) * n + zgate * hs;
          atomicAdd(&agg[(size_t)tail[e] * H_ + h], ex_s[ph * 64 + le] * msg);
        }
      }
    }
    __syncthreads();
  }
}

// ---- out = LayerNorm(relu((agg_raw/(den+eps)) @ Wh^T)), in place over d_out ----
__global__ __launch_bounds__(256) void k_out(
    const float* __restrict__ WhT, const float* __restrict__ ln_g, const float* __restrict__ ln_b,
    const float* __restrict__ den, float* __restrict__ out)
{
  __shared__ __align__(16) float a_s[16][H_];
  __shared__ float o_s[16][H_];
  __shared__ float mu_s[16], rs_s[16];
  const int tid = threadIdx.x;
  const size_t r0 = (size_t)blockIdx.x * 16;

  for (int idx = tid; idx < 16 * H_; idx += 256) {
    int r = idx >> 7, j = idx & (H_ - 1);
    float dv = den[r0 + r] + 1e-6f;
    a_s[r][j] = out[(r0 + r) * H_ + j] / dv;
  }
  __syncthreads();

  const int col = tid & 15, rr = tid >> 4;
  float acc[8] = {};
  for (int k4 = 0; k4 < H_ / 4; ++k4) {
    float4 a = ((const float4*)a_s[rr])[k4];
#pragma unroll
    for (int kk = 0; kk < 4; ++kk) {
      const float4* wrow = (const float4*)(WhT + (size_t)(k4 * 4 + kk) * H_);
      float av = ((const float*)&a)[kk];
      float4 w0 = wrow[col];
      float4 w1 = wrow[16 + col];
      acc[0] += av * w0.x; acc[1] += av * w0.y; acc[2] += av * w0.z; acc[3] += av * w0.w;
      acc[4] += av * w1.x; acc[5] += av * w1.y; acc[6] += av * w1.z; acc[7] += av * w1.w;
    }
  }
  float s = 0.f, sq = 0.f;
#pragma unroll
  for (int ci = 0; ci < 8; ++ci) {
    float v = fmaxf(acc[ci], 0.f);
    acc[ci] = v; s += v; sq += v * v;
  }
#pragma unroll
  for (int ci = 0; ci < 4; ++ci) {
    o_s[rr][col * 4 + ci]      = acc[ci];
    o_s[rr][64 + col * 4 + ci] = acc[4 + ci];
  }
#pragma unroll
  for (int off = 1; off < 16; off <<= 1) { s += __shfl_xor(s, off); sq += __shfl_xor(sq, off); }
  if (col == 0) {
    float mu = s * (1.f / H_);
    mu_s[rr] = mu;
    rs_s[rr] = rsqrtf(sq * (1.f / H_) - mu * mu + 1e-5f);
  }
  __syncthreads();
  for (int idx = tid; idx < 16 * H_; idx += 256) {
    int r = idx >> 7, j = idx & (H_ - 1);
    out[(r0 + r) * H_ + j] = ln_g[j] * (o_s[r][j] - mu_s[r]) * rs_s[r] + ln_b[j];
  }
}

extern "C" void kernel_launch(void* const* d_in, const int* in_sizes, int n_in,
                              void* d_out, int out_size, void* d_ws, size_t ws_size,
                              hipStream_t stream) {
  (void)in_sizes; (void)n_in; (void)ws_size;
  const int* head = (const int*)d_in[0];
  const int* rel  = (const int*)d_in[1];
  const int* ent  = (const int*)d_in[2];
  const int* tail = (const int*)d_in[3];
  const int* qidx = (const int*)d_in[4];
  const float* node_emb  = (const float*)d_in[5];
  const float* ent_table = (const float*)d_in[6];
  const float* rel_table = (const float*)d_in[7];
  const float* Ws   = (const float*)d_in[8];
  const float* Wr   = (const float*)d_in[9];
  const float* Wqr  = (const float*)d_in[10];
  const float* b_qr = (const float*)d_in[11];
  const float* Wa   = (const float*)d_in[12];
  const float* b_a  = (const float*)d_in[13];
  const float* W_ih = (const float*)d_in[14];
  const float* W_hh = (const float*)d_in[15];
  const float* b_ih = (const float*)d_in[16];
  const float* b_hh = (const float*)d_in[17];
  const float* Wh   = (const float*)d_in[18];
  const float* ln_g = (const float*)d_in[19];
  const float* ln_b = (const float*)d_in[20];
  float* out = (float*)d_out;

  // ws: den f32[N] | Wcat bf16[640*512] | WhT f32[128*128]
  float* den = (float*)d_ws;
  unsigned short* Wcat = (unsigned short*)(den + N_NEW_);
  float* WhT = (float*)((char*)d_ws + 400000 + 640 * 512 * 2);

  hipMemsetAsync(den, 0, N_NEW_ * sizeof(float), stream);
  hipMemsetAsync(d_out, 0, (size_t)out_size * sizeof(float), stream);

  k_prep<<<(640 * 512 + 255) / 256, 256, 0, stream>>>(Ws, Wr, Wqr, W_ih, W_hh, Wcat);
  k_transpose<<<(128 * 128 + 255) / 256, 256, 0, stream>>>(Wh, WhT, 128, 128);

  k_edge<<<(E_TOT + 127) / 128, 640, 0, stream>>>(
      head, rel, ent, tail, qidx, node_emb, ent_table, rel_table,
      Wcat, b_qr, Wa, b_a, b_ih, b_hh, den, out);

  k_out<<<N_NEW_ / 16, 256, 0, stream>>>(WhT, ln_g, ln_b, den, out);
}

// Round 3
// 1739.867 us; speedup vs baseline: 2.7514x; 1.0505x over previous
//
#include <hip/hip_runtime.h>

// Problem constants.
#define E_TOT   500000
#define N_NEW_  100000
#define H_      128
#define D_      100
#define NBLK_E  ((E_TOT + 127) / 128)       // 3907
#define PERMN   (NBLK_E * 128)              // 500096

typedef short bf16x8 __attribute__((ext_vector_type(8)));
typedef float f32x4  __attribute__((ext_vector_type(4)));

__device__ __forceinline__ unsigned short f2bf(float f) {
  unsigned u = __float_as_uint(f);
  u += 0x7fffu + ((u >> 16) & 1u);       // RNE
  return (unsigned short)(u >> 16);
}
__device__ __forceinline__ float sigm(float x) { return 1.f / (1.f + expf(-x)); }

// dst[c*R + r] = src[r*C + c]
__global__ void k_transpose(const float* __restrict__ src, float* __restrict__ dst, int R, int C) {
  int idx = blockIdx.x * 256 + threadIdx.x;
  if (idx < R * C) {
    int r = idx / C, c = idx - r * C;
    dst[(size_t)c * R + r] = src[idx];
  }
}

// Build the 640x512 bf16 weight atlas (see R2 comments; unchanged).
__global__ void k_prep(const float* __restrict__ Ws, const float* __restrict__ Wr,
                       const float* __restrict__ Wqr, const float* __restrict__ Wih,
                       const float* __restrict__ Whh, unsigned short* __restrict__ Wcat) {
  int idx = blockIdx.x * 256 + threadIdx.x;
  if (idx >= 640 * 512) return;
  int o = idx >> 9, k = idx & 511;
  int rg = k >> 7, cr = k & 127;
  int ch = o >> 7, oo = o & 127;
  float v = 0.f;
  if (ch == 0) {
    if (rg == 0) v = Ws[oo * 128 + cr];
    else if (rg == 1) { if (cr < 100) v = Wr[oo * 100 + cr]; }
    else if (rg == 2) { if (cr < 100) v = Wqr[oo * 100 + cr]; }
  } else if (ch == 1 || ch == 2) {
    int g = (ch - 1) * 128 + oo;
    if (rg == 0) v = Whh[g * 128 + cr];
    else if (rg == 1) { if (cr < 100) v = Wih[g * 200 + 100 + cr]; }
    else if (rg == 3) { if (cr < 100) v = Wih[g * 200 + cr]; }
  } else if (ch == 3) {
    int g = 256 + oo;
    if (rg == 1) { if (cr < 100) v = Wih[g * 200 + 100 + cr]; }
    else if (rg == 3) { if (cr < 100) v = Wih[g * 200 + cr]; }
  } else {
    int g = 256 + oo;
    if (rg == 0) v = Whh[g * 128 + cr];
  }
  Wcat[idx] = f2bf(v);
}

// ---- counting sort of edges by tail ----
__global__ void k_hist(const int* __restrict__ tail, int* __restrict__ cnt) {
  int e = blockIdx.x * 256 + threadIdx.x;
  if (e < E_TOT) atomicAdd(&cnt[tail[e]], 1);
}
__global__ void k_scan1(int* __restrict__ cnt, int* __restrict__ bsum) {
  __shared__ int s[512];
  int gid = blockIdx.x * 512 + threadIdx.x;
  int v = (gid < N_NEW_) ? cnt[gid] : 0;
  s[threadIdx.x] = v;
  __syncthreads();
  for (int off = 1; off < 512; off <<= 1) {
    int add = (threadIdx.x >= off) ? s[threadIdx.x - off] : 0;
    __syncthreads();
    s[threadIdx.x] += add;
    __syncthreads();
  }
  if (gid < N_NEW_) cnt[gid] = s[threadIdx.x] - v;     // exclusive, in place
  if (threadIdx.x == 511) bsum[blockIdx.x] = s[511];
}
__global__ void k_scan2(int* __restrict__ bsum, int nb) {
  if (threadIdx.x == 0 && blockIdx.x == 0) {
    int acc = 0;
    for (int i = 0; i < nb; ++i) { int v = bsum[i]; bsum[i] = acc; acc += v; }
  }
}
__global__ void k_scan3(int* __restrict__ cnt, const int* __restrict__ bsum) {
  int i = blockIdx.x * 256 + threadIdx.x;
  if (i < N_NEW_) cnt[i] += bsum[i >> 9];
}
__global__ void k_scatter(const int* __restrict__ tail, int* __restrict__ cur,
                          int* __restrict__ perm) {
  int e = blockIdx.x * 256 + threadIdx.x;
  if (e < E_TOT) {
    int pos = atomicAdd(&cur[tail[e]], 1);
    perm[pos] = e;
  }
}

__device__ __forceinline__ void gather8(const float* __restrict__ tbl, const int* __restrict__ idp,
                                        int w, int c0, int pe, float g8[8]) {
  bool ev = (pe >= 0);
  int ix = ev ? idp[pe] : 0;
  const float* src = tbl + (size_t)ix * w + c0;
  if (ev && c0 + 8 <= w) {
    float4 v0 = ((const float4*)src)[0];
    float4 v1 = ((const float4*)src)[1];
    g8[0] = v0.x; g8[1] = v0.y; g8[2] = v0.z; g8[3] = v0.w;
    g8[4] = v1.x; g8[5] = v1.y; g8[6] = v1.z; g8[7] = v1.w;
  } else {
#pragma unroll
    for (int j = 0; j < 8; ++j) g8[j] = (ev && (c0 + j) < w) ? src[j] : 0.f;
  }
}

// ---- Fused edge kernel over tail-sorted edges (via perm). 128 edges/block, 640 thr = 10 waves.
__global__ __launch_bounds__(640) void k_edge(
    const int* __restrict__ perm,
    const int* __restrict__ head, const int* __restrict__ rel, const int* __restrict__ ent,
    const int* __restrict__ tail, const int* __restrict__ qidx,
    const float* __restrict__ node_emb, const float* __restrict__ ent_table,
    const float* __restrict__ rel_table,
    const unsigned short* __restrict__ Wcat,
    const float* __restrict__ b_qr, const float* __restrict__ Wa, const float* __restrict__ b_a,
    const float* __restrict__ b_ih, const float* __restrict__ b_hh,
    float* __restrict__ den, float* __restrict__ agg)
{
  __shared__ __align__(16) char smem[4 * 64 * 130 * 4];              // 133,120 B
  unsigned short (*A)[128][40] = (unsigned short (*)[128][40])smem;  // main loop (20.5 KB)
  float (*G)[64][130] = (float (*)[64][130])smem;                    // epilogue gate exchange
  __shared__ float ex_s[128];
  __shared__ int pe_s[128], tl_s[128], hd_s[128];

  const int t = threadIdx.x;
  const int wid = t >> 6, lane = t & 63;
  const int c = wid >> 1, wm = wid & 1;     // chunk 0..4, M-half
  const int l15 = lane & 15, l4 = lane >> 4;
  const int e0 = blockIdx.x * 128;
  const int se = t >> 2, q = t & 3;         // stager: edge-in-block, quad
  const bool stager = (t < 512);

  if (t < 128) {
    int pe = perm[e0 + t];                  // pad entries are -1 (memset 0xFF)
    if (pe < 0 || pe >= E_TOT) pe = -1;
    pe_s[t] = pe;
    tl_s[t] = (pe >= 0) ? tail[pe] : -1;
    hd_s[t] = (pe >= 0) ? head[pe] : 0;
  }
  __syncthreads();

  f32x4 acc[4][8];
  const f32x4 zz = {0.f, 0.f, 0.f, 0.f};
#pragma unroll
  for (int i = 0; i < 4; ++i)
#pragma unroll
    for (int j = 0; j < 8; ++j) acc[i][j] = zz;

  float g8[8];

  if (stager) {
    gather8(node_emb, head, 128, q * 8, pe_s[se], g8);
    bf16x8 pk;
#pragma unroll
    for (int j = 0; j < 8; ++j) pk[j] = (short)f2bf(g8[j]);
    *(bf16x8*)&A[0][se][q * 8] = pk;
  }
  __syncthreads();

#pragma unroll
  for (int kt = 0; kt < 16; ++kt) {
    const int buf = kt & 1;
    if (kt + 1 < 16 && stager) {            // T14: issue next tile's gathers early
      int rg = (kt + 1) >> 2, sub = (kt + 1) & 3;
      const float* tb = (rg == 0) ? node_emb : (rg == 3) ? ent_table : rel_table;
      const int* ip = (rg == 0) ? head : (rg == 1) ? rel : (rg == 2) ? qidx : ent;
      int w = (rg == 0) ? 128 : 100;
      gather8(tb, ip, w, sub * 32 + q * 8, pe_s[se], g8);
    }
    bool act = (c == 0) ? (kt < 12)
             : (c <= 2) ? (kt < 8 || kt >= 12)
             : (c == 3) ? ((kt >= 4 && kt < 8) || kt >= 12)
                        : (kt < 4);
    if (act) {
      bf16x8 bfr[8], afr[4];
#pragma unroll
      for (int ni = 0; ni < 8; ++ni)
        bfr[ni] = *(const bf16x8*)(Wcat + ((size_t)(c * 128 + ni * 16 + l15) * 512 + kt * 32 + l4 * 8));
#pragma unroll
      for (int mi = 0; mi < 4; ++mi)
        afr[mi] = *(const bf16x8*)&A[buf][wm * 64 + mi * 16 + l15][l4 * 8];
#pragma unroll
      for (int mi = 0; mi < 4; ++mi)
#pragma unroll
        for (int ni = 0; ni < 8; ++ni)
          acc[mi][ni] = __builtin_amdgcn_mfma_f32_16x16x32_bf16(afr[mi], bfr[ni], acc[mi][ni], 0, 0, 0);
    }
    __syncthreads();
    if (kt + 1 < 16 && stager) {
      bf16x8 pk;
#pragma unroll
      for (int j = 0; j < 8; ++j) pk[j] = (short)f2bf(g8[j]);
      *(bf16x8*)&A[buf ^ 1][se][q * 8] = pk;
    }
    __syncthreads();
  }

  // ---- epilogue 1: logits -> ex_s (c==0); gate biases (c>=1, registers only) ----
  if (c == 0) {
    float ba = b_a[0];
#pragma unroll
    for (int mi = 0; mi < 4; ++mi) {
      float p[4] = {0.f, 0.f, 0.f, 0.f};
#pragma unroll
      for (int ni = 0; ni < 8; ++ni) {
        int o = ni * 16 + l15;
        float bq = b_qr[o], wa = Wa[o];
#pragma unroll
        for (int r = 0; r < 4; ++r) p[r] += wa * fmaxf(acc[mi][ni][r] + bq, 0.f);
      }
#pragma unroll
      for (int off = 1; off < 16; off <<= 1) {
#pragma unroll
        for (int r = 0; r < 4; ++r) p[r] += __shfl_xor(p[r], off);
      }
      if (l15 == 0) {
#pragma unroll
        for (int r = 0; r < 4; ++r) {
          int el = wm * 64 + mi * 16 + l4 * 4 + r;
          ex_s[el] = expf(p[r] + ba);   // no max-sub: |logit| <~ 2, folded into den divide
        }
      }
    }
  } else {
#pragma unroll
    for (int ni = 0; ni < 8; ++ni) {
      int h = ni * 16 + l15;
      float bias = (c == 1) ? b_ih[h] + b_hh[h]
                 : (c == 2) ? b_ih[128 + h] + b_hh[128 + h]
                 : (c == 3) ? b_ih[256 + h]
                            : b_hh[256 + h];
#pragma unroll
      for (int mi = 0; mi < 4; ++mi)
#pragma unroll
        for (int r = 0; r < 4; ++r) acc[mi][ni][r] += bias;
    }
  }
  __syncthreads();   // ex_s complete; A dead -> G region free

  // ---- epilogue 2: two phases {G write -> barrier -> run-accumulated scatter} ----
#pragma unroll
  for (int ph = 0; ph < 2; ++ph) {
    if (c >= 1 && wm == ph) {
#pragma unroll
      for (int mi = 0; mi < 4; ++mi)
#pragma unroll
        for (int ni = 0; ni < 8; ++ni)
#pragma unroll
          for (int r = 0; r < 4; ++r)
            G[c - 1][mi * 16 + l4 * 4 + r][ni * 16 + l15] = acc[mi][ni][r];
    }
    if (ph == 0 && t < 128) {
      // den: run-leaders over sorted tails (one atomic per run)
      int tl = tl_s[t];
      bool lead = (tl >= 0) && (t == 0 || tl_s[t - 1] != tl);
      if (lead) {
        float s = 0.f;
        int i = t;
        while (i < 128 && tl_s[i] == tl) { s += ex_s[i]; ++i; }
        atomicAdd(&den[tl], s);
      }
    }
    __syncthreads();
    if (t < 512) {
      int h = t & 127, grp = t >> 7;
      float run = 0.f;
      int rt = -1;
      for (int k = 0; k < 16; ++k) {
        int lp = grp * 16 + k;            // row within this phase's 64
        int eg = ph * 64 + lp;            // block-local edge
        int tl = tl_s[eg];
        if (tl >= 0) {
          float rgate = sigm(G[0][lp][h]);
          float zgate = sigm(G[1][lp][h]);
          float n = tanhf(G[2][lp][h] + rgate * G[3][lp][h]);
          float hs = node_emb[(size_t)hd_s[eg] * H_ + h];
          float v = ex_s[eg] * ((1.f - zgate) * n + zgate * hs);
          if (tl != rt) {
            if (rt >= 0) atomicAdd(&agg[(size_t)rt * H_ + h], run);
            run = 0.f; rt = tl;
          }
          run += v;
        }
      }
      if (rt >= 0) atomicAdd(&agg[(size_t)rt * H_ + h], run);
    }
    __syncthreads();
  }
}

// ---- out = LayerNorm(relu((agg_raw/(den+eps)) @ Wh^T)), in place over d_out ----
__global__ __launch_bounds__(256) void k_out(
    const float* __restrict__ WhT, const float* __restrict__ ln_g, const float* __restrict__ ln_b,
    const float* __restrict__ den, float* __restrict__ out)
{
  __shared__ __align__(16) float a_s[16][H_];
  __shared__ float o_s[16][H_];
  __shared__ float mu_s[16], rs_s[16];
  const int tid = threadIdx.x;
  const size_t r0 = (size_t)blockIdx.x * 16;

  for (int idx = tid; idx < 16 * H_; idx += 256) {
    int r = idx >> 7, j = idx & (H_ - 1);
    float dv = den[r0 + r] + 1e-6f;
    a_s[r][j] = out[(r0 + r) * H_ + j] / dv;
  }
  __syncthreads();

  const int col = tid & 15, rr = tid >> 4;
  float acc[8] = {};
  for (int k4 = 0; k4 < H_ / 4; ++k4) {
    float4 a = ((const float4*)a_s[rr])[k4];
#pragma unroll
    for (int kk = 0; kk < 4; ++kk) {
      const float4* wrow = (const float4*)(WhT + (size_t)(k4 * 4 + kk) * H_);
      float av = ((const float*)&a)[kk];
      float4 w0 = wrow[col];
      float4 w1 = wrow[16 + col];
      acc[0] += av * w0.x; acc[1] += av * w0.y; acc[2] += av * w0.z; acc[3] += av * w0.w;
      acc[4] += av * w1.x; acc[5] += av * w1.y; acc[6] += av * w1.z; acc[7] += av * w1.w;
    }
  }
  float s = 0.f, sq = 0.f;
#pragma unroll
  for (int ci = 0; ci < 8; ++ci) {
    float v = fmaxf(acc[ci], 0.f);
    acc[ci] = v; s += v; sq += v * v;
  }
#pragma unroll
  for (int ci = 0; ci < 4; ++ci) {
    o_s[rr][col * 4 + ci]      = acc[ci];
    o_s[rr][64 + col * 4 + ci] = acc[4 + ci];
  }
#pragma unroll
  for (int off = 1; off < 16; off <<= 1) { s += __shfl_xor(s, off); sq += __shfl_xor(sq, off); }
  if (col == 0) {
    float mu = s * (1.f / H_);
    mu_s[rr] = mu;
    rs_s[rr] = rsqrtf(sq * (1.f / H_) - mu * mu + 1e-5f);
  }
  __syncthreads();
  for (int idx = tid; idx < 16 * H_; idx += 256) {
    int r = idx >> 7, j = idx & (H_ - 1);
    out[(r0 + r) * H_ + j] = ln_g[j] * (o_s[r][j] - mu_s[r]) * rs_s[r] + ln_b[j];
  }
}

extern "C" void kernel_launch(void* const* d_in, const int* in_sizes, int n_in,
                              void* d_out, int out_size, void* d_ws, size_t ws_size,
                              hipStream_t stream) {
  (void)in_sizes; (void)n_in; (void)ws_size;
  const int* head = (const int*)d_in[0];
  const int* rel  = (const int*)d_in[1];
  const int* ent  = (const int*)d_in[2];
  const int* tail = (const int*)d_in[3];
  const int* qidx = (const int*)d_in[4];
  const float* node_emb  = (const float*)d_in[5];
  const float* ent_table = (const float*)d_in[6];
  const float* rel_table = (const float*)d_in[7];
  const float* Ws   = (const float*)d_in[8];
  const float* Wr   = (const float*)d_in[9];
  const float* Wqr  = (const float*)d_in[10];
  const float* b_qr = (const float*)d_in[11];
  const float* Wa   = (const float*)d_in[12];
  const float* b_a  = (const float*)d_in[13];
  const float* W_ih = (const float*)d_in[14];
  const float* W_hh = (const float*)d_in[15];
  const float* b_ih = (const float*)d_in[16];
  const float* b_hh = (const float*)d_in[17];
  const float* Wh   = (const float*)d_in[18];
  const float* ln_g = (const float*)d_in[19];
  const float* ln_b = (const float*)d_in[20];
  float* out = (float*)d_out;

  // ws layout (16B-aligned sections):
  float* den = (float*)d_ws;                                    // 400,000 B
  unsigned short* Wcat = (unsigned short*)(den + N_NEW_);       // 655,360 B
  float* WhT = (float*)(Wcat + 640 * 512);                      //  65,536 B
  int* cnt   = (int*)(WhT + 128 * 128);                         // 400,000 B
  int* bsum  = cnt + N_NEW_;                                    //   2,048 B (196 used)
  int* perm  = bsum + 512;                                      // 2,000,384 B

  hipMemsetAsync(den, 0, N_NEW_ * sizeof(float), stream);
  hipMemsetAsync(d_out, 0, (size_t)out_size * sizeof(float), stream);
  hipMemsetAsync(cnt, 0, N_NEW_ * sizeof(int), stream);
  hipMemsetAsync(perm + E_TOT, 0xFF, (PERMN - E_TOT) * sizeof(int), stream);  // pad = -1

  k_prep<<<(640 * 512 + 255) / 256, 256, 0, stream>>>(Ws, Wr, Wqr, W_ih, W_hh, Wcat);
  k_transpose<<<(128 * 128 + 255) / 256, 256, 0, stream>>>(Wh, WhT, 128, 128);

  // counting sort by tail
  k_hist<<<(E_TOT + 255) / 256, 256, 0, stream>>>(tail, cnt);
  k_scan1<<<(N_NEW_ + 511) / 512, 512, 0, stream>>>(cnt, bsum);
  k_scan2<<<1, 64, 0, stream>>>(bsum, (N_NEW_ + 511) / 512);
  k_scan3<<<(N_NEW_ + 255) / 256, 256, 0, stream>>>(cnt, bsum);
  k_scatter<<<(E_TOT + 255) / 256, 256, 0, stream>>>(tail, cnt, perm);

  k_edge<<<NBLK_E, 640, 0, stream>>>(
      perm, head, rel, ent, tail, qidx, node_emb, ent_table, rel_table,
      Wcat, b_qr, Wa, b_a, b_ih, b_hh, den, out);

  k_out<<<N_NEW_ / 16, 256, 0, stream>>>(WhT, ln_g, ln_b, den, out);
}